// Round 2
// baseline (96008.276 us; speedup 1.0000x reference)
//
#include <hip/hip_runtime.h>
#include <stdint.h>

#define NB 256
#define PERIOD 30

__device__ __forceinline__ float frcp(float x){ return __builtin_amdgcn_rcpf(x); }

// tanh(x) = 1 - 2/(exp(2x)+1); exp via native v_exp, rcp via v_rcp (1-ulp each)
__device__ __forceinline__ float fast_tanh(float x){
  float e = __expf(2.0f*x);
  return fmaf(-2.0f, frcp(e + 1.0f), 1.0f);
}

// Threefry-2x32, 20 rounds, key = (0, 42)  [jax.random.key(42)]
__device__ __forceinline__ void threefry2x32_k42(uint32_t x0, uint32_t x1,
                                                 uint32_t& o0, uint32_t& o1){
  const uint32_t ks0 = 0u;
  const uint32_t ks1 = 42u;
  const uint32_t ks2 = 0u ^ 42u ^ 0x1BD11BDAu;
  x0 += ks0; x1 += ks1;
#define TFR(rot) { x0 += x1; x1 = (x1 << (rot)) | (x1 >> (32 - (rot))); x1 ^= x0; }
  TFR(13) TFR(15) TFR(26) TFR(6)
  x0 += ks1; x1 += ks2 + 1u;
  TFR(17) TFR(29) TFR(16) TFR(24)
  x0 += ks2; x1 += ks0 + 2u;
  TFR(13) TFR(15) TFR(26) TFR(6)
  x0 += ks0; x1 += ks1 + 3u;
  TFR(17) TFR(29) TFR(16) TFR(24)
  x0 += ks1; x1 += ks2 + 4u;
  TFR(13) TFR(15) TFR(26) TFR(6)
  x0 += ks2; x1 += ks0 + 5u;
#undef TFR
  o0 = x0; o1 = x1;
}

// Mirror jax.random.normal f32 (XLA erfinv polynomial)
__device__ __forceinline__ float normal_from_bits(uint32_t bits){
  float f = __uint_as_float((bits >> 9) | 0x3f800000u) - 1.0f;   // [0,1)
  const float lo = -0.99999994f;
  float u = fmaf(f, 2.0f, lo);
  u = fmaxf(u, lo);
  float w = -log1pf(-u*u);
  float p;
  if (w < 5.0f){
    float ww = w - 2.5f;
    p = 2.81022636e-08f;
    p = fmaf(p, ww, 3.43273939e-07f);
    p = fmaf(p, ww, -3.5233877e-06f);
    p = fmaf(p, ww, -4.39150654e-06f);
    p = fmaf(p, ww, 0.00021858087f);
    p = fmaf(p, ww, -0.00125372503f);
    p = fmaf(p, ww, -0.00417768164f);
    p = fmaf(p, ww, 0.246640727f);
    p = fmaf(p, ww, 1.50140941f);
  } else {
    float ww = sqrtf(w) - 3.0f;
    p = -0.000200214257f;
    p = fmaf(p, ww, 0.000100950558f);
    p = fmaf(p, ww, 0.00134934322f);
    p = fmaf(p, ww, -0.00367342844f);
    p = fmaf(p, ww, 0.00573950773f);
    p = fmaf(p, ww, -0.0076224613f);
    p = fmaf(p, ww, 0.00943887047f);
    p = fmaf(p, ww, 1.00167406f);
    p = fmaf(p, ww, 2.83297682f);
  }
  return 1.41421356f * (p * u);
}

// Network + analytic JVPs w.r.t. (y2, y3), weights in LDS.
__device__ __forceinline__ void net_eval(float y2, float y3,
  const float* __restrict__ sWh,   // [3][64][32]
  const float* __restrict__ sW0,   // [2][64]
  const float* __restrict__ sb0,   // [64]
  const float* __restrict__ sbh,   // [3][32]
  const float* __restrict__ sWo,   // [3][32]
  const float* __restrict__ sbo,   // [3]
  float& q1, float& q2, float& q3,
  float& s11, float& s21, float& s31,
  float& s12, float& s22, float& s32)
{
  float q[3], sA[3], sB[3];
#pragma unroll
  for (int k = 0; k < 3; ++k){
    const float* Wh = sWh + k * 2048;
    const float* bh = sbh + k * 32;
    const float* Wo = sWo + k * 32;

    float at[32], a2[32], a3[32];
#pragma unroll
    for (int i = 0; i < 32; ++i){ at[i] = bh[i]; a2[i] = 0.0f; a3[i] = 0.0f; }

    for (int j = 0; j < 64; ++j){
      float w0a = sW0[j];
      float w0b = sW0[64 + j];
      float pre = fmaf(y2, w0a, fmaf(y3, w0b, sb0[j]));
      float h  = fast_tanh(pre);
      float u  = fmaf(-h, h, 1.0f);               // 1 - h^2
      float gA = u * w0a;
      float gB = u * w0b;
      const float4* wr4 = (const float4*)(Wh + j * 32);
#pragma unroll
      for (int v = 0; v < 8; ++v){
        float4 w = wr4[v];
#pragma unroll
        for (int c = 0; c < 4; ++c){
          int i = v * 4 + c;
          float wv = (c==0) ? w.x : (c==1) ? w.y : (c==2) ? w.z : w.w;
          at[i] = fmaf(h,  wv, at[i]);
          a2[i] = fmaf(gA, wv, a2[i]);
          a3[i] = fmaf(gB, wv, a3[i]);
        }
      }
    }

    float accq = 0.0f, accA = 0.0f, accB = 0.0f;
#pragma unroll
    for (int i = 0; i < 32; ++i){
      float t  = fast_tanh(at[i]);
      float dt = fmaf(-t, t, 1.0f);               // 1 - t^2
      float wo = Wo[i];
      accq = fmaf(t, wo, accq);
      accA = fmaf(dt * a2[i], wo, accA);
      accB = fmaf(dt * a3[i], wo, accB);
    }
    float qq = __expf(accq + sbo[k]);
    q[k]  = qq;
    sA[k] = 0.03f * accA;                         // SIGMA * dq/dy2 / q
    sB[k] = 0.03f * accB;
  }
  q1 = q[0]; q2 = q[1]; q3 = q[2];
  s11 = sA[0]; s21 = sA[1]; s31 = sA[2];
  s12 = sB[0]; s22 = sB[1]; s32 = sB[2];
}

__global__ __launch_bounds__(NB, 3)
void sim_kernel(const float* __restrict__ Y,
  const float* __restrict__ W0,  const float* __restrict__ b0,
  const float* __restrict__ Wh1, const float* __restrict__ bh1,
  const float* __restrict__ Wo1, const float* __restrict__ bo1,
  const float* __restrict__ Wh2, const float* __restrict__ bh2,
  const float* __restrict__ Wo2, const float* __restrict__ bo2,
  const float* __restrict__ Wh3, const float* __restrict__ bh3,
  const float* __restrict__ Wo3, const float* __restrict__ bo3,
  float* __restrict__ out, int n)
{
  // ---- stage weights to LDS (once per block) ----
  __shared__ float sWh[3 * 2048];   // 24 KB
  __shared__ float sW0[128];
  __shared__ float sb0[64];
  __shared__ float sbh[96];
  __shared__ float sWo[96];
  __shared__ float sbo[3];

  for (int idx = threadIdx.x; idx < 2048; idx += NB){
    sWh[idx]        = Wh1[idx];
    sWh[2048 + idx] = Wh2[idx];
    sWh[4096 + idx] = Wh3[idx];
  }
  if (threadIdx.x < 128) sW0[threadIdx.x] = W0[threadIdx.x];
  if (threadIdx.x < 64)  sb0[threadIdx.x] = b0[threadIdx.x];
  if (threadIdx.x < 32){
    sbh[threadIdx.x]      = bh1[threadIdx.x];
    sbh[32 + threadIdx.x] = bh2[threadIdx.x];
    sbh[64 + threadIdx.x] = bh3[threadIdx.x];
    sWo[threadIdx.x]      = Wo1[threadIdx.x];
    sWo[32 + threadIdx.x] = Wo2[threadIdx.x];
    sWo[64 + threadIdx.x] = Wo3[threadIdx.x];
  }
  if (threadIdx.x == 0){ sbo[0] = bo1[0]; sbo[1] = bo2[0]; sbo[2] = bo3[0]; }
  __syncthreads();

  const int gid = blockIdx.x * NB + threadIdx.x;
  const int ii  = (gid < n) ? gid : (n - 1);
  const float valid = (gid < n) ? 1.0f : 0.0f;

  const float2 yv = ((const float2*)Y)[ii];
  const float y2 = yv.x, y3 = yv.y;

  const float GAMMA = 1.2f, DT = 0.005f, SIGMA = 0.03f;
  const float KAPPA = 0.2f, YBAR = 2.0f, RHO = 0.03f, Bc = 1.0f, Cc = 0.1f;

  float q1,q2,q3,s11,s21,s31,s12,s22,s32;
  net_eval(y2, y3, sWh, sW0, sb0, sbh, sWo, sbo,
           q1,q2,q3,s11,s21,s31,s12,s22,s32);
  float Y2 = y2, Y3 = y3;
  float loss = 0.0f;

  for (int t = 0; t < PERIOD; ++t){
    // --- noise: partitionable threefry rollout, counter = flat index ---
    uint32_t idx0 = 2u * ((uint32_t)t * (uint32_t)n + (uint32_t)ii);
    uint32_t a0, a1, c0, c1;
    threefry2x32_k42(0u, idx0,      a0, a1);
    threefry2x32_k42(0u, idx0 + 1u, c0, c1);
    float dZ1 = 0.070710678f * normal_from_bits(a0 ^ a1);
    float dZ2 = 0.070710678f * normal_from_bits(c0 ^ c1);

    // --- step math (mirror reference, f32) ---
    float Wt  = q1 + q2 + q3;
    float q1h = q1 / Wt;
    float q2h = q2 / Wt;
    float q3h = 1.0f - q1h - q2h;
    float q1sq = q1 * q1;
    float c   = Bc*q1 - Cc*q1sq + Y2 + Y3;
    float bq  = Bc*q1 - 2.0f*Cc*q1sq;
    float sc1 = fmaf(bq, s11, SIGMA);
    float sc2 = fmaf(bq, s12, SIGMA);
    float sW1 = q1*s11 + q2*s21 + q3*s31;
    float sW2 = q1*s12 + q2*s22 + q3*s32;
    float sJ1 = 6.0f * (sc1/c - sW1/Wt);
    float sJ2 = 6.0f * (sc2/c - sW2/Wt);
    float d11 = s11*s11 + s12*s12;
    float d12 = s11*s21 + s12*s22;
    float d13 = s11*s31 + s12*s32;
    float d22 = s21*s21 + s22*s22;
    float d23 = s21*s31 + s22*s32;
    float d33 = s31*s31 + s32*s32;
    const float oneMG = 1.0f - GAMMA;   // -0.2
    float p1 = GAMMA*(q1h*d11 + q2h*d12 + q3h*d13) - oneMG*(sJ1*s11 + sJ2*s12);
    float p2 = GAMMA*(q1h*d12 + q2h*d22 + q3h*d23) - oneMG*(sJ1*s21 + sJ2*s22);
    float p3 = GAMMA*(q1h*d13 + q2h*d23 + q3h*d33) - oneMG*(sJ1*s31 + sJ2*s32);
    float muY2 = KAPPA * (YBAR - Y2);
    float muY3 = KAPPA * (YBAR - Y3);
    float r = RHO + GAMMA*(bq*(p1 - (Bc - Cc*q1)) - Cc*q1sq*d11 + muY2 + muY3)/c
                  - 1.32f*(sc1*sc1 + sc2*sc2)/(c*c);
    r = r / (1.0f - GAMMA*bq/c);
    float mu1 = r + p1 - (Bc - Cc*q1);
    float mu2 = r + p2 - Y2/q2;
    float mu3 = r + p3 - Y3/q3;
    float q1n = q1 * (1.0f + mu1*DT + s11*dZ1 + s12*dZ2);
    float q2n = q2 * (1.0f + mu2*DT + s21*dZ1 + s22*dZ2);
    float q3n = q3 * (1.0f + mu3*DT + s31*dZ1 + s32*dZ2);
    float Y2n = Y2 + muY2*DT + SIGMA*dZ1;
    float Y3n = Y3 + muY3*DT + SIGMA*dZ2;

    // --- network at new point (also refreshes s-state) ---
    float qt1, qt2, qt3;
    net_eval(Y2n, Y3n, sWh, sW0, sb0, sbh, sWo, sbo,
             qt1,qt2,qt3, s11,s21,s31,s12,s22,s32);

    float e1 = q1n - qt1, e2 = q2n - qt2, e3 = q3n - qt3;
    loss += e1*e1 + e2*e2 + e3*e3;

    q1 = q1n; q2 = q2n; q3 = q3n; Y2 = Y2n; Y3 = Y3n;
  }

  loss *= valid * (1.0f / ((float)15000000));   // / (n * PERIOD)

  // --- block reduction -> one atomic per block ---
#pragma unroll
  for (int off = 32; off > 0; off >>= 1)
    loss += __shfl_down(loss, off, 64);
  __shared__ float sred[NB / 64];
  const int lane = threadIdx.x & 63;
  const int wv   = threadIdx.x >> 6;
  if (lane == 0) sred[wv] = loss;
  __syncthreads();
  if (threadIdx.x == 0){
    float s = 0.0f;
#pragma unroll
    for (int w = 0; w < NB / 64; ++w) s += sred[w];
    atomicAdd(out, s);
  }
}

extern "C" void kernel_launch(void* const* d_in, const int* in_sizes, int n_in,
                              void* d_out, int out_size, void* d_ws, size_t ws_size,
                              hipStream_t stream)
{
  const float* Y   = (const float*)d_in[0];
  const float* W0  = (const float*)d_in[1];
  const float* b0  = (const float*)d_in[2];
  const float* Wh1 = (const float*)d_in[3];
  const float* bh1 = (const float*)d_in[4];
  const float* Wo1 = (const float*)d_in[5];
  const float* bo1 = (const float*)d_in[6];
  const float* Wh2 = (const float*)d_in[7];
  const float* bh2 = (const float*)d_in[8];
  const float* Wo2 = (const float*)d_in[9];
  const float* bo2 = (const float*)d_in[10];
  const float* Wh3 = (const float*)d_in[11];
  const float* bh3 = (const float*)d_in[12];
  const float* Wo3 = (const float*)d_in[13];
  const float* bo3 = (const float*)d_in[14];

  const int n = in_sizes[0] / 2;

  hipMemsetAsync(d_out, 0, sizeof(float), stream);

  const int grid = (n + NB - 1) / NB;
  sim_kernel<<<grid, NB, 0, stream>>>(Y,
      W0, b0, Wh1, bh1, Wo1, bo1, Wh2, bh2, Wo2, bo2, Wh3, bh3, Wo3, bo3,
      (float*)d_out, n);
}

// Round 3
// 22761.021 us; speedup vs baseline: 4.2181x; 4.2181x over previous
//
#include <hip/hip_runtime.h>
#include <stdint.h>

#define NB 256
#define PERIOD 30

__device__ __forceinline__ float frcp(float x){ return __builtin_amdgcn_rcpf(x); }

// tanh(x) = 1 - 2/(exp(2x)+1); exp via native v_exp, rcp via v_rcp (1-ulp each)
__device__ __forceinline__ float fast_tanh(float x){
  float e = __expf(2.0f*x);
  return fmaf(-2.0f, frcp(e + 1.0f), 1.0f);
}

// Threefry-2x32, 20 rounds, key = (0, 42)  [jax.random.key(42)]
__device__ __forceinline__ void threefry2x32_k42(uint32_t x0, uint32_t x1,
                                                 uint32_t& o0, uint32_t& o1){
  const uint32_t ks0 = 0u;
  const uint32_t ks1 = 42u;
  const uint32_t ks2 = 0u ^ 42u ^ 0x1BD11BDAu;
  x0 += ks0; x1 += ks1;
#define TFR(rot) { x0 += x1; x1 = (x1 << (rot)) | (x1 >> (32 - (rot))); x1 ^= x0; }
  TFR(13) TFR(15) TFR(26) TFR(6)
  x0 += ks1; x1 += ks2 + 1u;
  TFR(17) TFR(29) TFR(16) TFR(24)
  x0 += ks2; x1 += ks0 + 2u;
  TFR(13) TFR(15) TFR(26) TFR(6)
  x0 += ks0; x1 += ks1 + 3u;
  TFR(17) TFR(29) TFR(16) TFR(24)
  x0 += ks1; x1 += ks2 + 4u;
  TFR(13) TFR(15) TFR(26) TFR(6)
  x0 += ks2; x1 += ks0 + 5u;
#undef TFR
  o0 = x0; o1 = x1;
}

// Mirror jax.random.normal f32 (XLA erfinv polynomial)
__device__ __forceinline__ float normal_from_bits(uint32_t bits){
  float f = __uint_as_float((bits >> 9) | 0x3f800000u) - 1.0f;   // [0,1)
  const float lo = -0.99999994f;
  float u = fmaf(f, 2.0f, lo);
  u = fmaxf(u, lo);
  float w = -log1pf(-u*u);
  float p;
  if (w < 5.0f){
    float ww = w - 2.5f;
    p = 2.81022636e-08f;
    p = fmaf(p, ww, 3.43273939e-07f);
    p = fmaf(p, ww, -3.5233877e-06f);
    p = fmaf(p, ww, -4.39150654e-06f);
    p = fmaf(p, ww, 0.00021858087f);
    p = fmaf(p, ww, -0.00125372503f);
    p = fmaf(p, ww, -0.00417768164f);
    p = fmaf(p, ww, 0.246640727f);
    p = fmaf(p, ww, 1.50140941f);
  } else {
    float ww = sqrtf(w) - 3.0f;
    p = -0.000200214257f;
    p = fmaf(p, ww, 0.000100950558f);
    p = fmaf(p, ww, 0.00134934322f);
    p = fmaf(p, ww, -0.00367342844f);
    p = fmaf(p, ww, 0.00573950773f);
    p = fmaf(p, ww, -0.0076224613f);
    p = fmaf(p, ww, 0.00943887047f);
    p = fmaf(p, ww, 1.00167406f);
    p = fmaf(p, ww, 2.83297682f);
  }
  return 1.41421356f * (p * u);
}

// Network + analytic JVPs w.r.t. (y2, y3), weights in LDS.
// i-dimension split in halves of 16 -> only 48 live accumulators (VGPR diet).
__device__ __forceinline__ void net_eval(float y2, float y3,
  const float* __restrict__ sWh,   // [3][64][32]
  const float* __restrict__ sIn,   // [64][4] = {W0[0,j], W0[1,j], b0[j], 0}
  const float* __restrict__ sbh,   // [3][32]
  const float* __restrict__ sWo,   // [3][32]
  const float* __restrict__ sbo,   // [3]
  float& q1, float& q2, float& q3,
  float& s11, float& s21, float& s31,
  float& s12, float& s22, float& s32)
{
  float q[3], sA[3], sB[3];
#pragma unroll
  for (int k = 0; k < 3; ++k){
    const float* Wh = sWh + k * 2048;
    const float* bh = sbh + k * 32;
    const float* Wo = sWo + k * 32;
    float accq = 0.0f, accA = 0.0f, accB = 0.0f;

#pragma unroll
    for (int half = 0; half < 2; ++half){
      float at[16], a2[16], a3[16];
#pragma unroll
      for (int i = 0; i < 16; ++i){
        at[i] = bh[half * 16 + i]; a2[i] = 0.0f; a3[i] = 0.0f;
      }

      for (int j = 0; j < 64; ++j){
        const float* inj = sIn + j * 4;
        float w0a = inj[0];
        float w0b = inj[1];
        float pre = fmaf(y2, w0a, fmaf(y3, w0b, inj[2]));
        float h  = fast_tanh(pre);
        float u  = fmaf(-h, h, 1.0f);             // 1 - h^2
        float gA = u * w0a;
        float gB = u * w0b;
        const float* wr = Wh + j * 32 + half * 16;
#pragma unroll
        for (int i = 0; i < 16; ++i){
          float w = wr[i];
          at[i] = fmaf(h,  w, at[i]);
          a2[i] = fmaf(gA, w, a2[i]);
          a3[i] = fmaf(gB, w, a3[i]);
        }
      }

#pragma unroll
      for (int i = 0; i < 16; ++i){
        float t  = fast_tanh(at[i]);
        float dt = fmaf(-t, t, 1.0f);             // 1 - t^2
        float wo = Wo[half * 16 + i];
        accq = fmaf(t, wo, accq);
        accA = fmaf(dt * a2[i], wo, accA);
        accB = fmaf(dt * a3[i], wo, accB);
      }
    }

    q[k]  = __expf(accq + sbo[k]);
    sA[k] = 0.03f * accA;                         // SIGMA * dq/dy2 / q
    sB[k] = 0.03f * accB;
  }
  q1 = q[0]; q2 = q[1]; q3 = q[2];
  s11 = sA[0]; s21 = sA[1]; s31 = sA[2];
  s12 = sB[0]; s22 = sB[1]; s32 = sB[2];
}

__global__ __launch_bounds__(NB, 4)   // 48-acc structure fits 128 VGPR; no spill expected
void sim_kernel(const float* __restrict__ Y,
  const float* __restrict__ W0,  const float* __restrict__ b0,
  const float* __restrict__ Wh1, const float* __restrict__ bh1,
  const float* __restrict__ Wo1, const float* __restrict__ bo1,
  const float* __restrict__ Wh2, const float* __restrict__ bh2,
  const float* __restrict__ Wo2, const float* __restrict__ bo2,
  const float* __restrict__ Wh3, const float* __restrict__ bh3,
  const float* __restrict__ Wo3, const float* __restrict__ bo3,
  float* __restrict__ out, int n)
{
  // ---- stage weights to LDS (once per block) ----
  __shared__ float sWh[3 * 2048];   // 24 KB
  __shared__ float sIn[64 * 4];     // {w0a, w0b, b0, 0} per j
  __shared__ float sbh[96];
  __shared__ float sWo[96];
  __shared__ float sbo[3];

  for (int idx = threadIdx.x; idx < 2048; idx += NB){
    sWh[idx]        = Wh1[idx];
    sWh[2048 + idx] = Wh2[idx];
    sWh[4096 + idx] = Wh3[idx];
  }
  if (threadIdx.x < 64){
    int j = threadIdx.x;
    sIn[j * 4 + 0] = W0[j];
    sIn[j * 4 + 1] = W0[64 + j];
    sIn[j * 4 + 2] = b0[j];
    sIn[j * 4 + 3] = 0.0f;
  }
  if (threadIdx.x < 32){
    sbh[threadIdx.x]      = bh1[threadIdx.x];
    sbh[32 + threadIdx.x] = bh2[threadIdx.x];
    sbh[64 + threadIdx.x] = bh3[threadIdx.x];
    sWo[threadIdx.x]      = Wo1[threadIdx.x];
    sWo[32 + threadIdx.x] = Wo2[threadIdx.x];
    sWo[64 + threadIdx.x] = Wo3[threadIdx.x];
  }
  if (threadIdx.x == 0){ sbo[0] = bo1[0]; sbo[1] = bo2[0]; sbo[2] = bo3[0]; }
  __syncthreads();

  const int gid = blockIdx.x * NB + threadIdx.x;
  const int ii  = (gid < n) ? gid : (n - 1);
  const float valid = (gid < n) ? 1.0f : 0.0f;

  const float2 yv = ((const float2*)Y)[ii];
  const float y2 = yv.x, y3 = yv.y;

  const float GAMMA = 1.2f, DT = 0.005f, SIGMA = 0.03f;
  const float KAPPA = 0.2f, YBAR = 2.0f, RHO = 0.03f, Bc = 1.0f, Cc = 0.1f;

  float q1,q2,q3,s11,s21,s31,s12,s22,s32;
  net_eval(y2, y3, sWh, sIn, sbh, sWo, sbo,
           q1,q2,q3,s11,s21,s31,s12,s22,s32);
  float Y2 = y2, Y3 = y3;
  float loss = 0.0f;

  for (int t = 0; t < PERIOD; ++t){
    // --- noise: partitionable threefry rollout, counter = flat index ---
    uint32_t idx0 = 2u * ((uint32_t)t * (uint32_t)n + (uint32_t)ii);
    uint32_t a0, a1, c0, c1;
    threefry2x32_k42(0u, idx0,      a0, a1);
    threefry2x32_k42(0u, idx0 + 1u, c0, c1);
    float dZ1 = 0.070710678f * normal_from_bits(a0 ^ a1);
    float dZ2 = 0.070710678f * normal_from_bits(c0 ^ c1);

    // --- step math (mirror reference, f32) ---
    float Wt  = q1 + q2 + q3;
    float q1h = q1 / Wt;
    float q2h = q2 / Wt;
    float q3h = 1.0f - q1h - q2h;
    float q1sq = q1 * q1;
    float c   = Bc*q1 - Cc*q1sq + Y2 + Y3;
    float bq  = Bc*q1 - 2.0f*Cc*q1sq;
    float sc1 = fmaf(bq, s11, SIGMA);
    float sc2 = fmaf(bq, s12, SIGMA);
    float sW1 = q1*s11 + q2*s21 + q3*s31;
    float sW2 = q1*s12 + q2*s22 + q3*s32;
    float sJ1 = 6.0f * (sc1/c - sW1/Wt);
    float sJ2 = 6.0f * (sc2/c - sW2/Wt);
    float d11 = s11*s11 + s12*s12;
    float d12 = s11*s21 + s12*s22;
    float d13 = s11*s31 + s12*s32;
    float d22 = s21*s21 + s22*s22;
    float d23 = s21*s31 + s22*s32;
    float d33 = s31*s31 + s32*s32;
    const float oneMG = 1.0f - GAMMA;   // -0.2
    float p1 = GAMMA*(q1h*d11 + q2h*d12 + q3h*d13) - oneMG*(sJ1*s11 + sJ2*s12);
    float p2 = GAMMA*(q1h*d12 + q2h*d22 + q3h*d23) - oneMG*(sJ1*s21 + sJ2*s22);
    float p3 = GAMMA*(q1h*d13 + q2h*d23 + q3h*d33) - oneMG*(sJ1*s31 + sJ2*s32);
    float muY2 = KAPPA * (YBAR - Y2);
    float muY3 = KAPPA * (YBAR - Y3);
    float r = RHO + GAMMA*(bq*(p1 - (Bc - Cc*q1)) - Cc*q1sq*d11 + muY2 + muY3)/c
                  - 1.32f*(sc1*sc1 + sc2*sc2)/(c*c);
    r = r / (1.0f - GAMMA*bq/c);
    float mu1 = r + p1 - (Bc - Cc*q1);
    float mu2 = r + p2 - Y2/q2;
    float mu3 = r + p3 - Y3/q3;
    float q1n = q1 * (1.0f + mu1*DT + s11*dZ1 + s12*dZ2);
    float q2n = q2 * (1.0f + mu2*DT + s21*dZ1 + s22*dZ2);
    float q3n = q3 * (1.0f + mu3*DT + s31*dZ1 + s32*dZ2);
    float Y2n = Y2 + muY2*DT + SIGMA*dZ1;
    float Y3n = Y3 + muY3*DT + SIGMA*dZ2;

    // --- network at new point (also refreshes s-state) ---
    float qt1, qt2, qt3;
    net_eval(Y2n, Y3n, sWh, sIn, sbh, sWo, sbo,
             qt1,qt2,qt3, s11,s21,s31,s12,s22,s32);

    float e1 = q1n - qt1, e2 = q2n - qt2, e3 = q3n - qt3;
    loss += e1*e1 + e2*e2 + e3*e3;

    q1 = q1n; q2 = q2n; q3 = q3n; Y2 = Y2n; Y3 = Y3n;
  }

  loss *= valid * (1.0f / ((float)15000000));   // / (n * PERIOD)

  // --- block reduction -> one atomic per block ---
#pragma unroll
  for (int off = 32; off > 0; off >>= 1)
    loss += __shfl_down(loss, off, 64);
  __shared__ float sred[NB / 64];
  const int lane = threadIdx.x & 63;
  const int wv   = threadIdx.x >> 6;
  if (lane == 0) sred[wv] = loss;
  __syncthreads();
  if (threadIdx.x == 0){
    float s = 0.0f;
#pragma unroll
    for (int w = 0; w < NB / 64; ++w) s += sred[w];
    atomicAdd(out, s);
  }
}

extern "C" void kernel_launch(void* const* d_in, const int* in_sizes, int n_in,
                              void* d_out, int out_size, void* d_ws, size_t ws_size,
                              hipStream_t stream)
{
  const float* Y   = (const float*)d_in[0];
  const float* W0  = (const float*)d_in[1];
  const float* b0  = (const float*)d_in[2];
  const float* Wh1 = (const float*)d_in[3];
  const float* bh1 = (const float*)d_in[4];
  const float* Wo1 = (const float*)d_in[5];
  const float* bo1 = (const float*)d_in[6];
  const float* Wh2 = (const float*)d_in[7];
  const float* bh2 = (const float*)d_in[8];
  const float* Wo2 = (const float*)d_in[9];
  const float* bo2 = (const float*)d_in[10];
  const float* Wh3 = (const float*)d_in[11];
  const float* bh3 = (const float*)d_in[12];
  const float* Wo3 = (const float*)d_in[13];
  const float* bo3 = (const float*)d_in[14];

  const int n = in_sizes[0] / 2;

  hipMemsetAsync(d_out, 0, sizeof(float), stream);

  const int grid = (n + NB - 1) / NB;
  sim_kernel<<<grid, NB, 0, stream>>>(Y,
      W0, b0, Wh1, bh1, Wo1, bo1, Wh2, bh2, Wo2, bo2, Wh3, bh3, Wo3, bo3,
      (float*)d_out, n);
}

// Round 4
// 15439.810 us; speedup vs baseline: 6.2182x; 1.4742x over previous
//
#include <hip/hip_runtime.h>
#include <stdint.h>

#define NB 256
#define PERIOD 30

__device__ __forceinline__ float frcp(float x){ return __builtin_amdgcn_rcpf(x); }

// tanh(x) = 1 - 2/(exp(2x)+1); exp via native v_exp, rcp via v_rcp (1-ulp each)
__device__ __forceinline__ float fast_tanh(float x){
  float e = __expf(2.0f*x);
  return fmaf(-2.0f, frcp(e + 1.0f), 1.0f);
}

// Threefry-2x32, 20 rounds, key = (0, 42)  [jax.random.key(42)]
__device__ __forceinline__ void threefry2x32_k42(uint32_t x0, uint32_t x1,
                                                 uint32_t& o0, uint32_t& o1){
  const uint32_t ks0 = 0u;
  const uint32_t ks1 = 42u;
  const uint32_t ks2 = 0u ^ 42u ^ 0x1BD11BDAu;
  x0 += ks0; x1 += ks1;
#define TFR(rot) { x0 += x1; x1 = (x1 << (rot)) | (x1 >> (32 - (rot))); x1 ^= x0; }
  TFR(13) TFR(15) TFR(26) TFR(6)
  x0 += ks1; x1 += ks2 + 1u;
  TFR(17) TFR(29) TFR(16) TFR(24)
  x0 += ks2; x1 += ks0 + 2u;
  TFR(13) TFR(15) TFR(26) TFR(6)
  x0 += ks0; x1 += ks1 + 3u;
  TFR(17) TFR(29) TFR(16) TFR(24)
  x0 += ks1; x1 += ks2 + 4u;
  TFR(13) TFR(15) TFR(26) TFR(6)
  x0 += ks2; x1 += ks0 + 5u;
#undef TFR
  o0 = x0; o1 = x1;
}

// Mirror jax.random.normal f32 (XLA erfinv polynomial)
__device__ __forceinline__ float normal_from_bits(uint32_t bits){
  float f = __uint_as_float((bits >> 9) | 0x3f800000u) - 1.0f;   // [0,1)
  const float lo = -0.99999994f;
  float u = fmaf(f, 2.0f, lo);
  u = fmaxf(u, lo);
  float w = -log1pf(-u*u);
  float p;
  if (w < 5.0f){
    float ww = w - 2.5f;
    p = 2.81022636e-08f;
    p = fmaf(p, ww, 3.43273939e-07f);
    p = fmaf(p, ww, -3.5233877e-06f);
    p = fmaf(p, ww, -4.39150654e-06f);
    p = fmaf(p, ww, 0.00021858087f);
    p = fmaf(p, ww, -0.00125372503f);
    p = fmaf(p, ww, -0.00417768164f);
    p = fmaf(p, ww, 0.246640727f);
    p = fmaf(p, ww, 1.50140941f);
  } else {
    float ww = sqrtf(w) - 3.0f;
    p = -0.000200214257f;
    p = fmaf(p, ww, 0.000100950558f);
    p = fmaf(p, ww, 0.00134934322f);
    p = fmaf(p, ww, -0.00367342844f);
    p = fmaf(p, ww, 0.00573950773f);
    p = fmaf(p, ww, -0.0076224613f);
    p = fmaf(p, ww, 0.00943887047f);
    p = fmaf(p, ww, 1.00167406f);
    p = fmaf(p, ww, 2.83297682f);
  }
  return 1.41421356f * (p * u);
}

// Network + analytic JVPs w.r.t. (y2, y3), weights in LDS.
// i-dimension split in halves of 16 -> only 48 live accumulators.
__device__ __forceinline__ void net_eval(float y2, float y3,
  const float* __restrict__ sWh,   // [3][64][32]
  const float* __restrict__ sIn,   // [64][4] = {W0[0,j], W0[1,j], b0[j], 0}
  const float* __restrict__ sbh,   // [3][32]
  const float* __restrict__ sWo,   // [3][32]
  const float* __restrict__ sbo,   // [3]
  float& q1, float& q2, float& q3,
  float& s11, float& s21, float& s31,
  float& s12, float& s22, float& s32)
{
  float q[3], sA[3], sB[3];
#pragma unroll
  for (int k = 0; k < 3; ++k){
    const float* Wh = sWh + k * 2048;
    const float* bh = sbh + k * 32;
    const float* Wo = sWo + k * 32;
    float accq = 0.0f, accA = 0.0f, accB = 0.0f;

#pragma unroll
    for (int half = 0; half < 2; ++half){
      float at[16], a2[16], a3[16];
#pragma unroll
      for (int i = 0; i < 16; ++i){
        at[i] = bh[half * 16 + i]; a2[i] = 0.0f; a3[i] = 0.0f;
      }

#pragma unroll 1                                  // keep rolled: cap VGPR pressure
      for (int j = 0; j < 64; ++j){
        const float* inj = sIn + j * 4;
        float w0a = inj[0];
        float w0b = inj[1];
        float pre = fmaf(y2, w0a, fmaf(y3, w0b, inj[2]));
        float h  = fast_tanh(pre);
        float u  = fmaf(-h, h, 1.0f);             // 1 - h^2
        float gA = u * w0a;
        float gB = u * w0b;
        const float* wr = Wh + j * 32 + half * 16;
#pragma unroll
        for (int i = 0; i < 16; ++i){
          float w = wr[i];
          at[i] = fmaf(h,  w, at[i]);
          a2[i] = fmaf(gA, w, a2[i]);
          a3[i] = fmaf(gB, w, a3[i]);
        }
      }

#pragma unroll
      for (int i = 0; i < 16; ++i){
        float t  = fast_tanh(at[i]);
        float dt = fmaf(-t, t, 1.0f);             // 1 - t^2
        float wo = Wo[half * 16 + i];
        accq = fmaf(t, wo, accq);
        accA = fmaf(dt * a2[i], wo, accA);
        accB = fmaf(dt * a3[i], wo, accB);
      }
    }

    q[k]  = __expf(accq + sbo[k]);
    sA[k] = 0.03f * accA;                         // SIGMA * dq/dy2 / q
    sB[k] = 0.03f * accB;
  }
  q1 = q[0]; q2 = q[1]; q3 = q[2];
  s11 = sA[0]; s21 = sA[1]; s31 = sA[2];
  s12 = sB[0]; s22 = sB[1]; s32 = sB[2];
}

// NOTE: no min-waves __launch_bounds__ arg — empirically ((256,3)->84 VGPR/210GB
// scratch, (256,4)->64 VGPR/42GB scratch) it forces the allocator to spill the
// accumulator arrays. Natural allocation (R1: 172 VGPR) was spill-free.
__global__ __launch_bounds__(NB)
void sim_kernel(const float* __restrict__ Y,
  const float* __restrict__ W0,  const float* __restrict__ b0,
  const float* __restrict__ Wh1, const float* __restrict__ bh1,
  const float* __restrict__ Wo1, const float* __restrict__ bo1,
  const float* __restrict__ Wh2, const float* __restrict__ bh2,
  const float* __restrict__ Wo2, const float* __restrict__ bo2,
  const float* __restrict__ Wh3, const float* __restrict__ bh3,
  const float* __restrict__ Wo3, const float* __restrict__ bo3,
  float* __restrict__ out, int n)
{
  // ---- stage weights to LDS (once per block) ----
  __shared__ float sWh[3 * 2048];   // 24 KB
  __shared__ float sIn[64 * 4];     // {w0a, w0b, b0, 0} per j
  __shared__ float sbh[96];
  __shared__ float sWo[96];
  __shared__ float sbo[3];

  for (int idx = threadIdx.x; idx < 2048; idx += NB){
    sWh[idx]        = Wh1[idx];
    sWh[2048 + idx] = Wh2[idx];
    sWh[4096 + idx] = Wh3[idx];
  }
  if (threadIdx.x < 64){
    int j = threadIdx.x;
    sIn[j * 4 + 0] = W0[j];
    sIn[j * 4 + 1] = W0[64 + j];
    sIn[j * 4 + 2] = b0[j];
    sIn[j * 4 + 3] = 0.0f;
  }
  if (threadIdx.x < 32){
    sbh[threadIdx.x]      = bh1[threadIdx.x];
    sbh[32 + threadIdx.x] = bh2[threadIdx.x];
    sbh[64 + threadIdx.x] = bh3[threadIdx.x];
    sWo[threadIdx.x]      = Wo1[threadIdx.x];
    sWo[32 + threadIdx.x] = Wo2[threadIdx.x];
    sWo[64 + threadIdx.x] = Wo3[threadIdx.x];
  }
  if (threadIdx.x == 0){ sbo[0] = bo1[0]; sbo[1] = bo2[0]; sbo[2] = bo3[0]; }
  __syncthreads();

  const int gid = blockIdx.x * NB + threadIdx.x;
  const int ii  = (gid < n) ? gid : (n - 1);
  const float valid = (gid < n) ? 1.0f : 0.0f;

  const float2 yv = ((const float2*)Y)[ii];
  const float y2 = yv.x, y3 = yv.y;

  const float GAMMA = 1.2f, DT = 0.005f, SIGMA = 0.03f;
  const float KAPPA = 0.2f, YBAR = 2.0f, RHO = 0.03f, Bc = 1.0f, Cc = 0.1f;

  float q1,q2,q3,s11,s21,s31,s12,s22,s32;
  net_eval(y2, y3, sWh, sIn, sbh, sWo, sbo,
           q1,q2,q3,s11,s21,s31,s12,s22,s32);
  float Y2 = y2, Y3 = y3;
  float loss = 0.0f;

  for (int t = 0; t < PERIOD; ++t){
    // --- noise: partitionable threefry rollout, counter = flat index ---
    uint32_t idx0 = 2u * ((uint32_t)t * (uint32_t)n + (uint32_t)ii);
    uint32_t a0, a1, c0, c1;
    threefry2x32_k42(0u, idx0,      a0, a1);
    threefry2x32_k42(0u, idx0 + 1u, c0, c1);
    float dZ1 = 0.070710678f * normal_from_bits(a0 ^ a1);
    float dZ2 = 0.070710678f * normal_from_bits(c0 ^ c1);

    // --- step math (mirror reference, f32) ---
    float Wt  = q1 + q2 + q3;
    float q1h = q1 / Wt;
    float q2h = q2 / Wt;
    float q3h = 1.0f - q1h - q2h;
    float q1sq = q1 * q1;
    float c   = Bc*q1 - Cc*q1sq + Y2 + Y3;
    float bq  = Bc*q1 - 2.0f*Cc*q1sq;
    float sc1 = fmaf(bq, s11, SIGMA);
    float sc2 = fmaf(bq, s12, SIGMA);
    float sW1 = q1*s11 + q2*s21 + q3*s31;
    float sW2 = q1*s12 + q2*s22 + q3*s32;
    float sJ1 = 6.0f * (sc1/c - sW1/Wt);
    float sJ2 = 6.0f * (sc2/c - sW2/Wt);
    float d11 = s11*s11 + s12*s12;
    float d12 = s11*s21 + s12*s22;
    float d13 = s11*s31 + s12*s32;
    float d22 = s21*s21 + s22*s22;
    float d23 = s21*s31 + s22*s32;
    float d33 = s31*s31 + s32*s32;
    const float oneMG = 1.0f - GAMMA;   // -0.2
    float p1 = GAMMA*(q1h*d11 + q2h*d12 + q3h*d13) - oneMG*(sJ1*s11 + sJ2*s12);
    float p2 = GAMMA*(q1h*d12 + q2h*d22 + q3h*d23) - oneMG*(sJ1*s21 + sJ2*s22);
    float p3 = GAMMA*(q1h*d13 + q2h*d23 + q3h*d33) - oneMG*(sJ1*s31 + sJ2*s32);
    float muY2 = KAPPA * (YBAR - Y2);
    float muY3 = KAPPA * (YBAR - Y3);
    float r = RHO + GAMMA*(bq*(p1 - (Bc - Cc*q1)) - Cc*q1sq*d11 + muY2 + muY3)/c
                  - 1.32f*(sc1*sc1 + sc2*sc2)/(c*c);
    r = r / (1.0f - GAMMA*bq/c);
    float mu1 = r + p1 - (Bc - Cc*q1);
    float mu2 = r + p2 - Y2/q2;
    float mu3 = r + p3 - Y3/q3;
    float q1n = q1 * (1.0f + mu1*DT + s11*dZ1 + s12*dZ2);
    float q2n = q2 * (1.0f + mu2*DT + s21*dZ1 + s22*dZ2);
    float q3n = q3 * (1.0f + mu3*DT + s31*dZ1 + s32*dZ2);
    float Y2n = Y2 + muY2*DT + SIGMA*dZ1;
    float Y3n = Y3 + muY3*DT + SIGMA*dZ2;

    // --- network at new point (also refreshes s-state) ---
    float qt1, qt2, qt3;
    net_eval(Y2n, Y3n, sWh, sIn, sbh, sWo, sbo,
             qt1,qt2,qt3, s11,s21,s31,s12,s22,s32);

    float e1 = q1n - qt1, e2 = q2n - qt2, e3 = q3n - qt3;
    loss += e1*e1 + e2*e2 + e3*e3;

    q1 = q1n; q2 = q2n; q3 = q3n; Y2 = Y2n; Y3 = Y3n;
  }

  loss *= valid * (1.0f / ((float)15000000));   // / (n * PERIOD)

  // --- block reduction -> one atomic per block ---
#pragma unroll
  for (int off = 32; off > 0; off >>= 1)
    loss += __shfl_down(loss, off, 64);
  __shared__ float sred[NB / 64];
  const int lane = threadIdx.x & 63;
  const int wv   = threadIdx.x >> 6;
  if (lane == 0) sred[wv] = loss;
  __syncthreads();
  if (threadIdx.x == 0){
    float s = 0.0f;
#pragma unroll
    for (int w = 0; w < NB / 64; ++w) s += sred[w];
    atomicAdd(out, s);
  }
}

extern "C" void kernel_launch(void* const* d_in, const int* in_sizes, int n_in,
                              void* d_out, int out_size, void* d_ws, size_t ws_size,
                              hipStream_t stream)
{
  const float* Y   = (const float*)d_in[0];
  const float* W0  = (const float*)d_in[1];
  const float* b0  = (const float*)d_in[2];
  const float* Wh1 = (const float*)d_in[3];
  const float* bh1 = (const float*)d_in[4];
  const float* Wo1 = (const float*)d_in[5];
  const float* bo1 = (const float*)d_in[6];
  const float* Wh2 = (const float*)d_in[7];
  const float* bh2 = (const float*)d_in[8];
  const float* Wo2 = (const float*)d_in[9];
  const float* bo2 = (const float*)d_in[10];
  const float* Wh3 = (const float*)d_in[11];
  const float* bh3 = (const float*)d_in[12];
  const float* Wo3 = (const float*)d_in[13];
  const float* bo3 = (const float*)d_in[14];

  const int n = in_sizes[0] / 2;

  hipMemsetAsync(d_out, 0, sizeof(float), stream);

  const int grid = (n + NB - 1) / NB;
  sim_kernel<<<grid, NB, 0, stream>>>(Y,
      W0, b0, Wh1, bh1, Wo1, bo1, Wh2, bh2, Wo2, bo2, Wh3, bh3, Wo3, bo3,
      (float*)d_out, n);
}

// Round 5
// 7864.978 us; speedup vs baseline: 12.2071x; 1.9631x over previous
//
#include <hip/hip_runtime.h>
#include <stdint.h>

#define NB 256
#define PERIOD 30

__device__ __forceinline__ float frcp(float x){ return __builtin_amdgcn_rcpf(x); }

// tanh(x) = 1 - 2/(exp(2x)+1); exp via native v_exp, rcp via v_rcp (1-ulp each)
__device__ __forceinline__ float fast_tanh(float x){
  float e = __expf(2.0f*x);
  return fmaf(-2.0f, frcp(e + 1.0f), 1.0f);
}

// Threefry-2x32, 20 rounds, key = (0, 42)  [jax.random.key(42)]
__device__ __forceinline__ void threefry2x32_k42(uint32_t x0, uint32_t x1,
                                                 uint32_t& o0, uint32_t& o1){
  const uint32_t ks0 = 0u;
  const uint32_t ks1 = 42u;
  const uint32_t ks2 = 0u ^ 42u ^ 0x1BD11BDAu;
  x0 += ks0; x1 += ks1;
#define TFR(rot) { x0 += x1; x1 = (x1 << (rot)) | (x1 >> (32 - (rot))); x1 ^= x0; }
  TFR(13) TFR(15) TFR(26) TFR(6)
  x0 += ks1; x1 += ks2 + 1u;
  TFR(17) TFR(29) TFR(16) TFR(24)
  x0 += ks2; x1 += ks0 + 2u;
  TFR(13) TFR(15) TFR(26) TFR(6)
  x0 += ks0; x1 += ks1 + 3u;
  TFR(17) TFR(29) TFR(16) TFR(24)
  x0 += ks1; x1 += ks2 + 4u;
  TFR(13) TFR(15) TFR(26) TFR(6)
  x0 += ks2; x1 += ks0 + 5u;
#undef TFR
  o0 = x0; o1 = x1;
}

// Mirror jax.random.normal f32 (XLA erfinv polynomial)
__device__ __forceinline__ float normal_from_bits(uint32_t bits){
  float f = __uint_as_float((bits >> 9) | 0x3f800000u) - 1.0f;   // [0,1)
  const float lo = -0.99999994f;
  float u = fmaf(f, 2.0f, lo);
  u = fmaxf(u, lo);
  float w = -log1pf(-u*u);
  float p;
  if (w < 5.0f){
    float ww = w - 2.5f;
    p = 2.81022636e-08f;
    p = fmaf(p, ww, 3.43273939e-07f);
    p = fmaf(p, ww, -3.5233877e-06f);
    p = fmaf(p, ww, -4.39150654e-06f);
    p = fmaf(p, ww, 0.00021858087f);
    p = fmaf(p, ww, -0.00125372503f);
    p = fmaf(p, ww, -0.00417768164f);
    p = fmaf(p, ww, 0.246640727f);
    p = fmaf(p, ww, 1.50140941f);
  } else {
    float ww = sqrtf(w) - 3.0f;
    p = -0.000200214257f;
    p = fmaf(p, ww, 0.000100950558f);
    p = fmaf(p, ww, 0.00134934322f);
    p = fmaf(p, ww, -0.00367342844f);
    p = fmaf(p, ww, 0.00573950773f);
    p = fmaf(p, ww, -0.0076224613f);
    p = fmaf(p, ww, 0.00943887047f);
    p = fmaf(p, ww, 1.00167406f);
    p = fmaf(p, ww, 2.83297682f);
  }
  return 1.41421356f * (p * u);
}

// Network + analytic JVPs w.r.t. (y2, y3), weights in LDS.
// 3 passes (one per head), 96 live accumulators per pass -> 96 independent
// FMA chains per j-header (amortizes tanh/ds_read latency).
__device__ __forceinline__ void net_eval(float y2, float y3,
  const float* __restrict__ sWh,   // [3][64][32]
  const float* __restrict__ sIn,   // [64][4] = {W0[0,j], W0[1,j], b0[j], 0}
  const float* __restrict__ sbh,   // [3][32]
  const float* __restrict__ sWo,   // [3][32]
  const float* __restrict__ sbo,   // [3]
  float& q1, float& q2, float& q3,
  float& s11, float& s21, float& s31,
  float& s12, float& s22, float& s32)
{
  float q[3], sA[3], sB[3];
#pragma unroll 1
  for (int k = 0; k < 3; ++k){
    const float* Wh = sWh + k * 2048;
    const float* bh = sbh + k * 32;
    const float* Wo = sWo + k * 32;

    float at[32], a2[32], a3[32];
#pragma unroll
    for (int i = 0; i < 32; ++i){
      at[i] = bh[i]; a2[i] = 0.0f; a3[i] = 0.0f;
    }

#pragma unroll 2                                  // overlap next header with FMAs
    for (int j = 0; j < 64; ++j){
      const float4 in4 = ((const float4*)sIn)[j];
      float pre = fmaf(y2, in4.x, fmaf(y3, in4.y, in4.z));
      float h  = fast_tanh(pre);
      float u  = fmaf(-h, h, 1.0f);               // 1 - h^2
      float gA = u * in4.x;
      float gB = u * in4.y;
      const float4* wr4 = (const float4*)(Wh + j * 32);
#pragma unroll
      for (int v = 0; v < 8; ++v){
        float4 w = wr4[v];
#pragma unroll
        for (int c = 0; c < 4; ++c){
          int i = v * 4 + c;
          float wv = (c==0) ? w.x : (c==1) ? w.y : (c==2) ? w.z : w.w;
          at[i] = fmaf(h,  wv, at[i]);
          a2[i] = fmaf(gA, wv, a2[i]);
          a3[i] = fmaf(gB, wv, a3[i]);
        }
      }
    }

    float accq = 0.0f, accA = 0.0f, accB = 0.0f;
#pragma unroll
    for (int i = 0; i < 32; ++i){
      float t  = fast_tanh(at[i]);
      float dt = fmaf(-t, t, 1.0f);               // 1 - t^2
      float wo = Wo[i];
      accq = fmaf(t, wo, accq);
      accA = fmaf(dt * a2[i], wo, accA);
      accB = fmaf(dt * a3[i], wo, accB);
    }

    q[k]  = __expf(accq + sbo[k]);
    sA[k] = 0.03f * accA;                         // SIGMA * dq/dy2 / q
    sB[k] = 0.03f * accB;
  }
  q1 = q[0]; q2 = q[1]; q3 = q[2];
  s11 = sA[0]; s21 = sA[1]; s31 = sA[2];
  s12 = sB[0]; s22 = sB[1]; s32 = sB[2];
}

// NOTE: no min-waves __launch_bounds__ arg — empirically ((256,3)->84 VGPR/210GB
// scratch, (256,4)->64 VGPR/42GB scratch) it forces the allocator to spill the
// accumulator arrays. Natural allocation is spill-free.
__global__ __launch_bounds__(NB)
void sim_kernel(const float* __restrict__ Y,
  const float* __restrict__ W0,  const float* __restrict__ b0,
  const float* __restrict__ Wh1, const float* __restrict__ bh1,
  const float* __restrict__ Wo1, const float* __restrict__ bo1,
  const float* __restrict__ Wh2, const float* __restrict__ bh2,
  const float* __restrict__ Wo2, const float* __restrict__ bo2,
  const float* __restrict__ Wh3, const float* __restrict__ bh3,
  const float* __restrict__ Wo3, const float* __restrict__ bo3,
  float* __restrict__ out, int n)
{
  // ---- stage weights to LDS (once per block) ----
  __shared__ float sWh[3 * 2048];   // 24 KB
  __shared__ float sIn[64 * 4];     // {w0a, w0b, b0, 0} per j
  __shared__ float sbh[96];
  __shared__ float sWo[96];
  __shared__ float sbo[3];

  for (int idx = threadIdx.x; idx < 2048; idx += NB){
    sWh[idx]        = Wh1[idx];
    sWh[2048 + idx] = Wh2[idx];
    sWh[4096 + idx] = Wh3[idx];
  }
  if (threadIdx.x < 64){
    int j = threadIdx.x;
    sIn[j * 4 + 0] = W0[j];
    sIn[j * 4 + 1] = W0[64 + j];
    sIn[j * 4 + 2] = b0[j];
    sIn[j * 4 + 3] = 0.0f;
  }
  if (threadIdx.x < 32){
    sbh[threadIdx.x]      = bh1[threadIdx.x];
    sbh[32 + threadIdx.x] = bh2[threadIdx.x];
    sbh[64 + threadIdx.x] = bh3[threadIdx.x];
    sWo[threadIdx.x]      = Wo1[threadIdx.x];
    sWo[32 + threadIdx.x] = Wo2[threadIdx.x];
    sWo[64 + threadIdx.x] = Wo3[threadIdx.x];
  }
  if (threadIdx.x == 0){ sbo[0] = bo1[0]; sbo[1] = bo2[0]; sbo[2] = bo3[0]; }
  __syncthreads();

  const int gid = blockIdx.x * NB + threadIdx.x;
  const int ii  = (gid < n) ? gid : (n - 1);
  const float valid = (gid < n) ? 1.0f : 0.0f;

  const float2 yv = ((const float2*)Y)[ii];
  const float y2 = yv.x, y3 = yv.y;

  const float GAMMA = 1.2f, DT = 0.005f, SIGMA = 0.03f;
  const float KAPPA = 0.2f, YBAR = 2.0f, RHO = 0.03f, Bc = 1.0f, Cc = 0.1f;

  float q1,q2,q3,s11,s21,s31,s12,s22,s32;
  net_eval(y2, y3, sWh, sIn, sbh, sWo, sbo,
           q1,q2,q3,s11,s21,s31,s12,s22,s32);
  float Y2 = y2, Y3 = y3;
  float loss = 0.0f;

  for (int t = 0; t < PERIOD; ++t){
    // --- noise: partitionable threefry rollout, counter = flat index ---
    uint32_t idx0 = 2u * ((uint32_t)t * (uint32_t)n + (uint32_t)ii);
    uint32_t a0, a1, c0, c1;
    threefry2x32_k42(0u, idx0,      a0, a1);
    threefry2x32_k42(0u, idx0 + 1u, c0, c1);
    float dZ1 = 0.070710678f * normal_from_bits(a0 ^ a1);
    float dZ2 = 0.070710678f * normal_from_bits(c0 ^ c1);

    // --- step math (mirror reference, f32) ---
    float Wt  = q1 + q2 + q3;
    float q1h = q1 / Wt;
    float q2h = q2 / Wt;
    float q3h = 1.0f - q1h - q2h;
    float q1sq = q1 * q1;
    float c   = Bc*q1 - Cc*q1sq + Y2 + Y3;
    float bq  = Bc*q1 - 2.0f*Cc*q1sq;
    float sc1 = fmaf(bq, s11, SIGMA);
    float sc2 = fmaf(bq, s12, SIGMA);
    float sW1 = q1*s11 + q2*s21 + q3*s31;
    float sW2 = q1*s12 + q2*s22 + q3*s32;
    float sJ1 = 6.0f * (sc1/c - sW1/Wt);
    float sJ2 = 6.0f * (sc2/c - sW2/Wt);
    float d11 = s11*s11 + s12*s12;
    float d12 = s11*s21 + s12*s22;
    float d13 = s11*s31 + s12*s32;
    float d22 = s21*s21 + s22*s22;
    float d23 = s21*s31 + s22*s32;
    float d33 = s31*s31 + s32*s32;
    const float oneMG = 1.0f - GAMMA;   // -0.2
    float p1 = GAMMA*(q1h*d11 + q2h*d12 + q3h*d13) - oneMG*(sJ1*s11 + sJ2*s12);
    float p2 = GAMMA*(q1h*d12 + q2h*d22 + q3h*d23) - oneMG*(sJ1*s21 + sJ2*s22);
    float p3 = GAMMA*(q1h*d13 + q2h*d23 + q3h*d33) - oneMG*(sJ1*s31 + sJ2*s32);
    float muY2 = KAPPA * (YBAR - Y2);
    float muY3 = KAPPA * (YBAR - Y3);
    float r = RHO + GAMMA*(bq*(p1 - (Bc - Cc*q1)) - Cc*q1sq*d11 + muY2 + muY3)/c
                  - 1.32f*(sc1*sc1 + sc2*sc2)/(c*c);
    r = r / (1.0f - GAMMA*bq/c);
    float mu1 = r + p1 - (Bc - Cc*q1);
    float mu2 = r + p2 - Y2/q2;
    float mu3 = r + p3 - Y3/q3;
    float q1n = q1 * (1.0f + mu1*DT + s11*dZ1 + s12*dZ2);
    float q2n = q2 * (1.0f + mu2*DT + s21*dZ1 + s22*dZ2);
    float q3n = q3 * (1.0f + mu3*DT + s31*dZ1 + s32*dZ2);
    float Y2n = Y2 + muY2*DT + SIGMA*dZ1;
    float Y3n = Y3 + muY3*DT + SIGMA*dZ2;

    // --- network at new point (also refreshes s-state) ---
    float qt1, qt2, qt3;
    net_eval(Y2n, Y3n, sWh, sIn, sbh, sWo, sbo,
             qt1,qt2,qt3, s11,s21,s31,s12,s22,s32);

    float e1 = q1n - qt1, e2 = q2n - qt2, e3 = q3n - qt3;
    loss += e1*e1 + e2*e2 + e3*e3;

    q1 = q1n; q2 = q2n; q3 = q3n; Y2 = Y2n; Y3 = Y3n;
  }

  loss *= valid * (1.0f / ((float)15000000));   // / (n * PERIOD)

  // --- block reduction -> one atomic per block ---
#pragma unroll
  for (int off = 32; off > 0; off >>= 1)
    loss += __shfl_down(loss, off, 64);
  __shared__ float sred[NB / 64];
  const int lane = threadIdx.x & 63;
  const int wv   = threadIdx.x >> 6;
  if (lane == 0) sred[wv] = loss;
  __syncthreads();
  if (threadIdx.x == 0){
    float s = 0.0f;
#pragma unroll
    for (int w = 0; w < NB / 64; ++w) s += sred[w];
    atomicAdd(out, s);
  }
}

extern "C" void kernel_launch(void* const* d_in, const int* in_sizes, int n_in,
                              void* d_out, int out_size, void* d_ws, size_t ws_size,
                              hipStream_t stream)
{
  const float* Y   = (const float*)d_in[0];
  const float* W0  = (const float*)d_in[1];
  const float* b0  = (const float*)d_in[2];
  const float* Wh1 = (const float*)d_in[3];
  const float* bh1 = (const float*)d_in[4];
  const float* Wo1 = (const float*)d_in[5];
  const float* bo1 = (const float*)d_in[6];
  const float* Wh2 = (const float*)d_in[7];
  const float* bh2 = (const float*)d_in[8];
  const float* Wo2 = (const float*)d_in[9];
  const float* bo2 = (const float*)d_in[10];
  const float* Wh3 = (const float*)d_in[11];
  const float* bh3 = (const float*)d_in[12];
  const float* Wo3 = (const float*)d_in[13];
  const float* bo3 = (const float*)d_in[14];

  const int n = in_sizes[0] / 2;

  hipMemsetAsync(d_out, 0, sizeof(float), stream);

  const int grid = (n + NB - 1) / NB;
  sim_kernel<<<grid, NB, 0, stream>>>(Y,
      W0, b0, Wh1, bh1, Wo1, bo1, Wh2, bh2, Wo2, bo2, Wh3, bh3, Wo3, bo3,
      (float*)d_out, n);
}

// Round 6
// 5219.703 us; speedup vs baseline: 18.3934x; 1.5068x over previous
//
#include <hip/hip_runtime.h>
#include <hip/hip_bf16.h>
#include <stdint.h>

#define NB 256
#define PERIOD 30

typedef __bf16  bf16x8 __attribute__((ext_vector_type(8)));
typedef float   f32x4  __attribute__((ext_vector_type(4)));
typedef unsigned int uint4v __attribute__((ext_vector_type(4)));

__device__ __forceinline__ float frcp(float x){ return __builtin_amdgcn_rcpf(x); }

// tanh(x) = 1 - 2/(exp(2x)+1)
__device__ __forceinline__ float fast_tanh(float x){
  float e = __expf(2.0f*x);
  return fmaf(-2.0f, frcp(e + 1.0f), 1.0f);
}

__device__ __forceinline__ unsigned int f2bfbits(float x){
  union { __hip_bfloat16 b; unsigned short u; } v;
  v.b = __float2bfloat16(x);          // RNE, matches XLA convert
  return (unsigned int)v.u;
}
__device__ __forceinline__ unsigned int pack2bf(float lo, float hi){
  return f2bfbits(lo) | (f2bfbits(hi) << 16);
}

// Threefry-2x32, 20 rounds, key = (0, 42)
__device__ __forceinline__ void threefry2x32_k42(uint32_t x0, uint32_t x1,
                                                 uint32_t& o0, uint32_t& o1){
  const uint32_t ks0 = 0u, ks1 = 42u, ks2 = 0u ^ 42u ^ 0x1BD11BDAu;
  x0 += ks0; x1 += ks1;
#define TFR(rot) { x0 += x1; x1 = (x1 << (rot)) | (x1 >> (32 - (rot))); x1 ^= x0; }
  TFR(13) TFR(15) TFR(26) TFR(6)
  x0 += ks1; x1 += ks2 + 1u;
  TFR(17) TFR(29) TFR(16) TFR(24)
  x0 += ks2; x1 += ks0 + 2u;
  TFR(13) TFR(15) TFR(26) TFR(6)
  x0 += ks0; x1 += ks1 + 3u;
  TFR(17) TFR(29) TFR(16) TFR(24)
  x0 += ks1; x1 += ks2 + 4u;
  TFR(13) TFR(15) TFR(26) TFR(6)
  x0 += ks2; x1 += ks0 + 5u;
#undef TFR
  o0 = x0; o1 = x1;
}

// Mirror jax.random.normal f32 (XLA erfinv polynomial)
__device__ __forceinline__ float normal_from_bits(uint32_t bits){
  float f = __uint_as_float((bits >> 9) | 0x3f800000u) - 1.0f;
  const float lo = -0.99999994f;
  float u = fmaf(f, 2.0f, lo);
  u = fmaxf(u, lo);
  float w = -log1pf(-u*u);
  float p;
  if (w < 5.0f){
    float ww = w - 2.5f;
    p = 2.81022636e-08f;
    p = fmaf(p, ww, 3.43273939e-07f);
    p = fmaf(p, ww, -3.5233877e-06f);
    p = fmaf(p, ww, -4.39150654e-06f);
    p = fmaf(p, ww, 0.00021858087f);
    p = fmaf(p, ww, -0.00125372503f);
    p = fmaf(p, ww, -0.00417768164f);
    p = fmaf(p, ww, 0.246640727f);
    p = fmaf(p, ww, 1.50140941f);
  } else {
    float ww = sqrtf(w) - 3.0f;
    p = -0.000200214257f;
    p = fmaf(p, ww, 0.000100950558f);
    p = fmaf(p, ww, 0.00134934322f);
    p = fmaf(p, ww, -0.00367342844f);
    p = fmaf(p, ww, 0.00573950773f);
    p = fmaf(p, ww, -0.0076224613f);
    p = fmaf(p, ww, 0.00943887047f);
    p = fmaf(p, ww, 1.00167406f);
    p = fmaf(p, ww, 2.83297682f);
  }
  return 1.41421356f * (p * u);
}

// MFMA net eval: per wave, A = [h | gA | gB] (64 samples x 64 k, bf16),
// B = Wh^T (96 n x 64 k, bf16, shared). C tail + col-reduce + LDS redistribute.
// XOR swizzle key = row&7 on bit 4-6 of byte addr (both write & read sides).
__device__ __forceinline__ void net_eval(
    float y2, float y3,
    const float* __restrict__ sIn,    // [64][4] f32 {w0a,w0b,b0,pad}
    char* sAw,                        // this wave's A buffer: [3][16][128B]
    const char* sBb,                  // B: [96][128B] swizzled
    float* scr,                       // this wave's [64][12] f32
    int colL, int grp,
    const float (*bh_v)[2], const float (*wo_v)[2], const float* bo_v,
    float& q1o, float& q2o, float& q3o,
    float& s11, float& s21, float& s31,
    float& s12, float& s22, float& s32)
{
  // ---- first layer (f32, per-lane = per-sample), pack bf16 rows ----
  unsigned int hp[32], gap[32], gbp[32];
#pragma unroll
  for (int d = 0; d < 32; ++d){
    float4 iA = ((const float4*)sIn)[2*d];
    float4 iB = ((const float4*)sIn)[2*d+1];
    float preA = fmaf(y2, iA.x, fmaf(y3, iA.y, iA.z));
    float preB = fmaf(y2, iB.x, fmaf(y3, iB.y, iB.z));
    float hA = fast_tanh(preA), hB = fast_tanh(preB);
    float uA = fmaf(-hA, hA, 1.0f), uB = fmaf(-hB, hB, 1.0f);
    hp[d]  = pack2bf(hA, hB);
    gap[d] = pack2bf(uA*iA.x, uB*iB.x);
    gbp[d] = pack2bf(uA*iA.y, uB*iB.y);
  }

  // ---- B fragments (12), cached for the whole eval ----
  bf16x8 bf[3][2][2];
#pragma unroll
  for (int hd = 0; hd < 3; ++hd)
#pragma unroll
    for (int nt = 0; nt < 2; ++nt)
#pragma unroll
      for (int kt = 0; kt < 2; ++kt){
        int nrow = hd*32 + nt*16 + colL;
        int off = nrow*128 + (((kt*64 + grp*16)) ^ ((colL & 7) << 4));
        bf[hd][nt][kt] = *(const bf16x8*)(sBb + off);
      }

  const float SIG = 0.03f;

#pragma unroll 1
  for (int st = 0; st < 4; ++st){
    // ---- stage this sample-tile's A rows (owning lanes only) ----
    if (grp == st){
      int row = colL;
#pragma unroll
      for (int w = 0; w < 8; ++w){
        int off = row*128 + ((w*16) ^ ((row & 7) << 4));
        *(uint4v*)(sAw + off) =
            uint4v{hp[w*4], hp[w*4+1], hp[w*4+2], hp[w*4+3]};
        *(uint4v*)(sAw + 2048 + off) =
            uint4v{gap[w*4], gap[w*4+1], gap[w*4+2], gap[w*4+3]};
        *(uint4v*)(sAw + 4096 + off) =
            uint4v{gbp[w*4], gbp[w*4+1], gbp[w*4+2], gbp[w*4+3]};
      }
    }
    // DS pipe is in-order per wave: reads below (same array) are safe;
    // compiler inserts lgkmcnt before register use.

    // ---- A fragments for this tile ----
    bf16x8 af[3][2];
#pragma unroll
    for (int m = 0; m < 3; ++m)
#pragma unroll
      for (int kt = 0; kt < 2; ++kt){
        int off = m*2048 + colL*128 + ((kt*64 + grp*16) ^ ((colL & 7) << 4));
        af[m][kt] = *(const bf16x8*)(sAw + off);
      }

#pragma unroll
    for (int hd = 0; hd < 3; ++hd){
      float aq[4] = {0,0,0,0}, aA[4] = {0,0,0,0}, aB[4] = {0,0,0,0};
#pragma unroll
      for (int nt = 0; nt < 2; ++nt){
        f32x4 cAT = {0,0,0,0}, cA2 = {0,0,0,0}, cA3 = {0,0,0,0};
#pragma unroll
        for (int kt = 0; kt < 2; ++kt){
          cAT = __builtin_amdgcn_mfma_f32_16x16x32_bf16(af[0][kt], bf[hd][nt][kt], cAT, 0, 0, 0);
          cA2 = __builtin_amdgcn_mfma_f32_16x16x32_bf16(af[1][kt], bf[hd][nt][kt], cA2, 0, 0, 0);
          cA3 = __builtin_amdgcn_mfma_f32_16x16x32_bf16(af[2][kt], bf[hd][nt][kt], cA3, 0, 0, 0);
        }
        float wo = wo_v[hd][nt], bh = bh_v[hd][nt];
#pragma unroll
        for (int r = 0; r < 4; ++r){
          float t  = fast_tanh(cAT[r] + bh);
          float dt = fmaf(-t, t, 1.0f);
          aq[r] = fmaf(t, wo, aq[r]);
          aA[r] = fmaf(dt * cA2[r], wo, aA[r]);
          aB[r] = fmaf(dt * cA3[r], wo, aB[r]);
        }
      }
      // reduce across the 16 col-lanes (bits 0-3)
#pragma unroll
      for (int r = 0; r < 4; ++r){
        float q = aq[r], A = aA[r], Bv = aB[r];
#pragma unroll
        for (int d = 1; d < 16; d <<= 1){
          q  += __shfl_xor(q,  d, 64);
          A  += __shfl_xor(A,  d, 64);
          Bv += __shfl_xor(Bv, d, 64);
        }
        if (colL == 0){
          int samp = st*16 + grp*4 + r;
          float qq = __expf(q + bo_v[hd]);
          *(f32x4*)(scr + samp*12 + hd*4) = f32x4{qq, SIG*A, SIG*Bv, 0.0f};
        }
      }
    }
  }

  // ---- read back own sample's 9 values ----
  int lane = grp*16 + colL;
  f32x4 h1 = *(const f32x4*)(scr + lane*12 + 0);
  f32x4 h2 = *(const f32x4*)(scr + lane*12 + 4);
  f32x4 h3 = *(const f32x4*)(scr + lane*12 + 8);
  q1o = h1.x; s11 = h1.y; s12 = h1.z;
  q2o = h2.x; s21 = h2.y; s22 = h2.z;
  q3o = h3.x; s31 = h3.y; s32 = h3.z;
}

// NOTE: no min-waves __launch_bounds__ arg — it forces accumulator spills
// ((256,3)->210GB, (256,4)->42GB scratch writes). Natural allocation is clean.
__global__ __launch_bounds__(NB)
void sim_kernel(const float* __restrict__ Y,
  const float* __restrict__ W0,  const float* __restrict__ b0,
  const float* __restrict__ Wh1, const float* __restrict__ bh1,
  const float* __restrict__ Wo1, const float* __restrict__ bo1,
  const float* __restrict__ Wh2, const float* __restrict__ bh2,
  const float* __restrict__ Wo2, const float* __restrict__ bo2,
  const float* __restrict__ Wh3, const float* __restrict__ bh3,
  const float* __restrict__ Wo3, const float* __restrict__ bo3,
  float* __restrict__ out, int n)
{
  __shared__ __align__(16) char  sB[96 * 128];        // Wh^T bf16, swizzled
  __shared__ __align__(16) char  sA[4][3 * 16 * 128]; // per-wave A chunks
  __shared__ __align__(16) float sScr[4][64 * 12];    // per-wave redistribute
  __shared__ __align__(16) float sIn[64 * 4];

  // ---- init B = Wh^T (bf16, swizzled) ----
  for (int e = threadIdx.x; e < 6144; e += NB){
    int hd = e >> 11, rem = e & 2047, j = rem >> 5, i = rem & 31;
    const float* W = (hd == 0) ? Wh1 : (hd == 1) ? Wh2 : Wh3;
    float v = W[j * 32 + i];
    int nrow = hd * 32 + i;
    int off = (nrow * 128 + j * 2) ^ ((nrow & 7) << 4);
    *(unsigned short*)(sB + off) = (unsigned short)f2bfbits(v);
  }
  if (threadIdx.x < 64){
    int j = threadIdx.x;
    sIn[j*4+0] = W0[j]; sIn[j*4+1] = W0[64+j]; sIn[j*4+2] = b0[j]; sIn[j*4+3] = 0.0f;
  }
  __syncthreads();

  const int wv   = threadIdx.x >> 6;
  const int lane = threadIdx.x & 63;
  const int colL = lane & 15;
  const int grp  = lane >> 4;
  char*  sAw = &sA[wv][0];
  float* scr = &sScr[wv][0];

  // per-lane second-layer constants
  float bh_v[3][2], wo_v[3][2], bo_v[3];
  {
    const float* BH[3] = {bh1, bh2, bh3};
    const float* WOp[3] = {Wo1, Wo2, Wo3};
#pragma unroll
    for (int hd = 0; hd < 3; ++hd){
#pragma unroll
      for (int nt = 0; nt < 2; ++nt){
        bh_v[hd][nt] = BH[hd][nt*16 + colL];
        wo_v[hd][nt] = WOp[hd][nt*16 + colL];
      }
    }
    bo_v[0] = bo1[0]; bo_v[1] = bo2[0]; bo_v[2] = bo3[0];
  }

  const int gid = blockIdx.x * NB + threadIdx.x;
  const int ii  = (gid < n) ? gid : (n - 1);
  const float valid = (gid < n) ? 1.0f : 0.0f;

  const float2 yv = ((const float2*)Y)[ii];
  const float y2 = yv.x, y3 = yv.y;

  const float GAMMA = 1.2f, DT = 0.005f, SIGMA = 0.03f;
  const float KAPPA = 0.2f, YBAR = 2.0f, RHO = 0.03f, Bc = 1.0f, Cc = 0.1f;

  float q1,q2,q3,s11,s21,s31,s12,s22,s32;
  net_eval(y2, y3, sIn, sAw, sB, scr, colL, grp, bh_v, wo_v, bo_v,
           q1,q2,q3,s11,s21,s31,s12,s22,s32);
  float Y2 = y2, Y3 = y3;
  float loss = 0.0f;

  for (int t = 0; t < PERIOD; ++t){
    // --- noise: threefry rollout, counter = flat index (bit-exact) ---
    uint32_t idx0 = 2u * ((uint32_t)t * (uint32_t)n + (uint32_t)ii);
    uint32_t a0, a1, c0, c1;
    threefry2x32_k42(0u, idx0,      a0, a1);
    threefry2x32_k42(0u, idx0 + 1u, c0, c1);
    float dZ1 = 0.070710678f * normal_from_bits(a0 ^ a1);
    float dZ2 = 0.070710678f * normal_from_bits(c0 ^ c1);

    // --- step math (mirror reference, f32) ---
    float Wt  = q1 + q2 + q3;
    float q1h = q1 / Wt;
    float q2h = q2 / Wt;
    float q3h = 1.0f - q1h - q2h;
    float q1sq = q1 * q1;
    float c   = Bc*q1 - Cc*q1sq + Y2 + Y3;
    float bq  = Bc*q1 - 2.0f*Cc*q1sq;
    float sc1 = fmaf(bq, s11, SIGMA);
    float sc2 = fmaf(bq, s12, SIGMA);
    float sW1 = q1*s11 + q2*s21 + q3*s31;
    float sW2 = q1*s12 + q2*s22 + q3*s32;
    float sJ1 = 6.0f * (sc1/c - sW1/Wt);
    float sJ2 = 6.0f * (sc2/c - sW2/Wt);
    float d11 = s11*s11 + s12*s12;
    float d12 = s11*s21 + s12*s22;
    float d13 = s11*s31 + s12*s32;
    float d22 = s21*s21 + s22*s22;
    float d23 = s21*s31 + s22*s32;
    float d33 = s31*s31 + s32*s32;
    const float oneMG = 1.0f - GAMMA;   // -0.2
    float p1 = GAMMA*(q1h*d11 + q2h*d12 + q3h*d13) - oneMG*(sJ1*s11 + sJ2*s12);
    float p2 = GAMMA*(q1h*d12 + q2h*d22 + q3h*d23) - oneMG*(sJ1*s21 + sJ2*s22);
    float p3 = GAMMA*(q1h*d13 + q2h*d23 + q3h*d33) - oneMG*(sJ1*s31 + sJ2*s32);
    float muY2 = KAPPA * (YBAR - Y2);
    float muY3 = KAPPA * (YBAR - Y3);
    float r = RHO + GAMMA*(bq*(p1 - (Bc - Cc*q1)) - Cc*q1sq*d11 + muY2 + muY3)/c
                  - 1.32f*(sc1*sc1 + sc2*sc2)/(c*c);
    r = r / (1.0f - GAMMA*bq/c);
    float mu1 = r + p1 - (Bc - Cc*q1);
    float mu2 = r + p2 - Y2/q2;
    float mu3 = r + p3 - Y3/q3;
    float q1n = q1 * (1.0f + mu1*DT + s11*dZ1 + s12*dZ2);
    float q2n = q2 * (1.0f + mu2*DT + s21*dZ1 + s22*dZ2);
    float q3n = q3 * (1.0f + mu3*DT + s31*dZ1 + s32*dZ2);
    float Y2n = Y2 + muY2*DT + SIGMA*dZ1;
    float Y3n = Y3 + muY3*DT + SIGMA*dZ2;

    float qt1, qt2, qt3;
    net_eval(Y2n, Y3n, sIn, sAw, sB, scr, colL, grp, bh_v, wo_v, bo_v,
             qt1,qt2,qt3, s11,s21,s31,s12,s22,s32);

    float e1 = q1n - qt1, e2 = q2n - qt2, e3 = q3n - qt3;
    loss += e1*e1 + e2*e2 + e3*e3;

    q1 = q1n; q2 = q2n; q3 = q3n; Y2 = Y2n; Y3 = Y3n;
  }

  loss *= valid * (1.0f / ((float)15000000));   // / (n * PERIOD)

  // --- block reduction -> one atomic per block ---
#pragma unroll
  for (int off = 32; off > 0; off >>= 1)
    loss += __shfl_down(loss, off, 64);
  __shared__ float sred[NB / 64];
  if (lane == 0) sred[wv] = loss;
  __syncthreads();
  if (threadIdx.x == 0){
    float s = 0.0f;
#pragma unroll
    for (int w = 0; w < NB / 64; ++w) s += sred[w];
    atomicAdd(out, s);
  }
}

extern "C" void kernel_launch(void* const* d_in, const int* in_sizes, int n_in,
                              void* d_out, int out_size, void* d_ws, size_t ws_size,
                              hipStream_t stream)
{
  const float* Y   = (const float*)d_in[0];
  const float* W0  = (const float*)d_in[1];
  const float* b0  = (const float*)d_in[2];
  const float* Wh1 = (const float*)d_in[3];
  const float* bh1 = (const float*)d_in[4];
  const float* Wo1 = (const float*)d_in[5];
  const float* bo1 = (const float*)d_in[6];
  const float* Wh2 = (const float*)d_in[7];
  const float* bh2 = (const float*)d_in[8];
  const float* Wo2 = (const float*)d_in[9];
  const float* bo2 = (const float*)d_in[10];
  const float* Wh3 = (const float*)d_in[11];
  const float* bh3 = (const float*)d_in[12];
  const float* Wo3 = (const float*)d_in[13];
  const float* bo3 = (const float*)d_in[14];

  const int n = in_sizes[0] / 2;

  hipMemsetAsync(d_out, 0, sizeof(float), stream);

  const int grid = (n + NB - 1) / NB;
  sim_kernel<<<grid, NB, 0, stream>>>(Y,
      W0, b0, Wh1, bh1, Wo1, bo1, Wh2, bh2, Wo2, bo2, Wh3, bh3, Wo3, bo3,
      (float*)d_out, n);
}